// Round 2
// baseline (5412.050 us; speedup 1.0000x reference)
//
#include <hip/hip_runtime.h>

// ---------- types / helpers ----------
typedef __bf16 bf16x8 __attribute__((ext_vector_type(8)));
typedef float  f32x4  __attribute__((ext_vector_type(4)));

__device__ __forceinline__ float bf2f(unsigned short u) {
    union { unsigned int i; float f; } x; x.i = ((unsigned int)u) << 16; return x.f;
}
__device__ __forceinline__ unsigned short f2bf(float f) {
    union { float f; unsigned int i; } x; x.f = f;
    unsigned int r = x.i + 0x7fff + ((x.i >> 16) & 1);   // RNE
    return (unsigned short)(r >> 16);
}

__device__ __forceinline__ void gload16(const void* g, void* l) {
    __builtin_amdgcn_global_load_lds(
        (const __attribute__((address_space(1))) void*)g,
        (__attribute__((address_space(3))) void*)l, 16, 0, 0);
}

// ---------- fp32 -> bf16 conversion (vectorized, grid-stride) ----------
__global__ __launch_bounds__(256) void cvt_f32_bf16(
    const float4* __restrict__ in, ushort4* __restrict__ out, long n4)
{
    long i = (long)blockIdx.x * blockDim.x + threadIdx.x;
    const long stride = (long)gridDim.x * blockDim.x;
    for (; i < n4; i += stride) {
        const float4 v = in[i];
        ushort4 o = { f2bf(v.x), f2bf(v.y), f2bf(v.z), f2bf(v.w) };
        out[i] = o;
    }
}

// ---------- NT GEMM: C[m,n] = sum_k A[m,k]*B[n,k] (+bias[n] fp32, opt relu) ----------
// A,B bf16 (ushort) row-major K-contiguous. C: bf16 (CT=ushort) or fp32 (CT=float).
// 128x128 tile, BK=32, 256 threads (4 waves in 2x2 of 64x64 sub-tiles).
// If pred_n >= 0: whole launch no-ops unless *eid_p == pred_n.
template<bool RELU, typename CT>
__global__ __launch_bounds__(256, 2) void gemm_nt(
    const ushort* __restrict__ A, long lda,
    const ushort* __restrict__ B, long ldb,
    const float* __restrict__ bias,
    CT* __restrict__ C, long ldc,
    int K, const int* eid_p, int pred_n)
{
    if (pred_n >= 0 && *eid_p != pred_n) return;

    __shared__ alignas(16) ushort As[128 * 32];
    __shared__ alignas(16) ushort Bs[128 * 32];

    const int t    = threadIdx.x;
    const int w    = t >> 6;
    const int lane = t & 63;
    const int lr   = lane & 15;
    const int lq   = lane >> 4;
    const int wm   = (w >> 1) * 64;
    const int wn   = (w & 1) * 64;
    const long m0  = (long)blockIdx.y * 128;
    const long n0  = (long)blockIdx.x * 128;

    // staging: thread t loads 16B: row = t>>2 (0..63), k-chunk = (t&3)*8
    const int srow   = t >> 2;
    const int schunk = (t & 3) * 8;
    const ushort* aG = A + (m0 + srow) * lda + schunk;
    const ushort* bG = B + (n0 + srow) * ldb + schunk;
    char* lA = (char*)As + w * 1024;   // wave-uniform LDS base; HW appends lane*16
    char* lB = (char*)Bs + w * 1024;

    f32x4 acc[4][4];
#pragma unroll
    for (int i = 0; i < 4; i++)
#pragma unroll
        for (int j = 0; j < 4; j++) acc[i][j] = (f32x4){0.f, 0.f, 0.f, 0.f};

    for (int kt = 0; kt < K; kt += 32) {
        gload16(aG,            lA);
        gload16(aG + 64 * lda, lA + 4096);
        gload16(bG,            lB);
        gload16(bG + 64 * ldb, lB + 4096);
        aG += 32; bG += 32;
        __syncthreads();

        bf16x8 af[4], bf[4];
#pragma unroll
        for (int i = 0; i < 4; i++)
            af[i] = *(const bf16x8*)&As[(wm + i * 16 + lr) * 32 + lq * 8];
#pragma unroll
        for (int j = 0; j < 4; j++)
            bf[j] = *(const bf16x8*)&Bs[(wn + j * 16 + lr) * 32 + lq * 8];
#pragma unroll
        for (int i = 0; i < 4; i++)
#pragma unroll
            for (int j = 0; j < 4; j++)
                acc[i][j] = __builtin_amdgcn_mfma_f32_16x16x32_bf16(af[i], bf[j], acc[i][j], 0, 0, 0);
        __syncthreads();
    }

    // epilogue: row = m0+wm+i*16+lq*4+r, col = n0+wn+j*16+lr
#pragma unroll
    for (int j = 0; j < 4; j++) {
        const long col = n0 + wn + j * 16 + lr;
        const float bv = bias[col];
#pragma unroll
        for (int i = 0; i < 4; i++) {
            const long rbase = m0 + wm + i * 16 + lq * 4;
#pragma unroll
            for (int r = 0; r < 4; r++) {
                float v = acc[i][j][r] + bv;
                if (RELU) v = fmaxf(v, 0.f);
                if constexpr (__is_same(CT, ushort)) C[(rbase + r) * ldc + col] = f2bf(v);
                else                                 C[(rbase + r) * ldc + col] = v;
            }
        }
    }
}

// ---------- attention over the expert axis ----------
// per (b,s)=m, head h (16): logits[n] = q.k[n]/8 + (n<=eid), softmax, o = sum attn*v.
// kv layout: row (m*8+n), 2048 wide: k @ [0,1024), v @ [1024,2048).
__global__ __launch_bounds__(256) void attn_kernel(
    const ushort* __restrict__ q, const ushort* __restrict__ kv,
    const int* __restrict__ eid_p, ushort* __restrict__ o3)
{
    const size_t m = blockIdx.x;
    const int t    = threadIdx.x;
    const int h    = t >> 4;
    const int d0   = (t & 15) * 4;
    const int eid  = *eid_p;

    const ushort4 qu = *(const ushort4*)(q + m * 1024 + h * 64 + d0);
    const float qv[4] = { bf2f(qu.x), bf2f(qu.y), bf2f(qu.z), bf2f(qu.w) };

    float l[8];
#pragma unroll
    for (int n = 0; n < 8; n++) {
        const ushort4 ku = *(const ushort4*)(kv + (m * 8 + n) * 2048 + h * 64 + d0);
        float p = qv[0] * bf2f(ku.x) + qv[1] * bf2f(ku.y) + qv[2] * bf2f(ku.z) + qv[3] * bf2f(ku.w);
        p += __shfl_xor(p, 1);
        p += __shfl_xor(p, 2);
        p += __shfl_xor(p, 4);
        p += __shfl_xor(p, 8);
        l[n] = p * 0.125f + ((n <= eid) ? 1.0f : 0.0f);
    }
    float mx = l[0];
#pragma unroll
    for (int n = 1; n < 8; n++) mx = fmaxf(mx, l[n]);
    float e[8], s = 0.f;
#pragma unroll
    for (int n = 0; n < 8; n++) { e[n] = __expf(l[n] - mx); s += e[n]; }
    const float inv = 1.f / s;

    float o[4] = {0.f, 0.f, 0.f, 0.f};
#pragma unroll
    for (int n = 0; n < 8; n++) {
        const ushort4 vu = *(const ushort4*)(kv + (m * 8 + n) * 2048 + 1024 + h * 64 + d0);
        const float a = e[n] * inv;
        o[0] += a * bf2f(vu.x); o[1] += a * bf2f(vu.y);
        o[2] += a * bf2f(vu.z); o[3] += a * bf2f(vu.w);
    }
    ushort4 ou = { f2bf(o[0]), f2bf(o[1]), f2bf(o[2]), f2bf(o[3]) };
    *(ushort4*)(o3 + m * 1024 + h * 64 + d0) = ou;
}

// ---------- launch ----------
extern "C" void kernel_launch(void* const* d_in, const int* in_sizes, int n_in,
                              void* d_out, int out_size, void* d_ws, size_t ws_size,
                              hipStream_t stream)
{
    const float* x   = (const float*)d_in[0];
    const float* w1  = (const float*)d_in[1];
    const float* b1  = (const float*)d_in[2];
    const float* w2  = (const float*)d_in[3];
    const float* b2  = (const float*)d_in[4];
    const float* ipw = (const float*)d_in[5];
    const float* ipb = (const float*)d_in[6];
    const float* ow  = (const float*)d_in[7];
    const float* ob  = (const float*)d_in[8];
    const int*   eid = (const int*)d_in[9];

    // ---- workspace layout (bytes) ----
    char* ws = (char*)d_ws;
    size_t off = 0;
    auto alloc = [&](size_t bytes) { char* p = ws + off; off += (bytes + 255) & ~(size_t)255; return p; };
    ushort* w1b  = (ushort*)alloc(8LL * 4096 * 1024 * 2);   //  67.1 MB
    ushort* w2b  = (ushort*)alloc(8LL * 1024 * 4096 * 2);   //  67.1 MB
    ushort* ipwb = (ushort*)alloc(3LL * 1024 * 1024 * 2);   //   6.3 MB
    ushort* owb  = (ushort*)alloc(1LL * 1024 * 1024 * 2);   //   2.1 MB
    ushort* xb   = (ushort*)alloc(8192LL * 1024 * 2);       //  16.8 MB
    ushort* kvb  = (ushort*)alloc(8192LL * 8 * 2048 * 2);   // 268.4 MB
    ushort* qb   = (ushort*)alloc(8192LL * 1024 * 2);       //  16.8 MB
    ushort* o3b  = (ushort*)alloc(8192LL * 8192);           //  16.8 MB  (1024 cols * 2B... kept 16.8MB slot)
    const size_t fixed = off;
    // per-chunk transients: h (Mc x 4096) + eo (Mc x 1024), bf16
    long Mc = 8192;
    while (Mc > 128 && fixed + (size_t)Mc * 5120 * 2 + 512 > ws_size) Mc >>= 1;
    ushort* hb  = (ushort*)alloc((size_t)Mc * 4096 * 2);
    ushort* eob = (ushort*)alloc((size_t)Mc * 1024 * 2);

    const dim3 blk(256);
    const dim3 cgrid(2048);

    // ---- fp32 -> bf16 conversions (weights + x); biases stay fp32 ----
    cvt_f32_bf16<<<cgrid, blk, 0, stream>>>((const float4*)w1,  (ushort4*)w1b,  8LL * 4096 * 1024 / 4);
    cvt_f32_bf16<<<cgrid, blk, 0, stream>>>((const float4*)w2,  (ushort4*)w2b,  8LL * 1024 * 4096 / 4);
    cvt_f32_bf16<<<cgrid, blk, 0, stream>>>((const float4*)ipw, (ushort4*)ipwb, 3LL * 1024 * 1024 / 4);
    cvt_f32_bf16<<<cgrid, blk, 0, stream>>>((const float4*)ow,  (ushort4*)owb,  1LL * 1024 * 1024 / 4);
    cvt_f32_bf16<<<cgrid, blk, 0, stream>>>((const float4*)x,   (ushort4*)xb,   8192LL * 1024 / 4);

    // ---- per M-chunk, per expert: MLP -> eo -> {kv, q} ----
    for (long m0 = 0; m0 < 8192; m0 += Mc) {
        for (int n = 0; n < 8; n++) {
            // h = relu(x @ w1[n]^T + b1[n]) : Mc x 4096, K=1024
            gemm_nt<true, ushort><<<dim3(32, Mc / 128), blk, 0, stream>>>(
                xb + m0 * 1024, 1024, w1b + (size_t)n * 4096 * 1024, 1024, b1 + (size_t)n * 4096,
                hb, 4096, 1024, eid, -1);
            // eo = h @ w2[n]^T + b2[n] : Mc x 1024, K=4096
            gemm_nt<false, ushort><<<dim3(8, Mc / 128), blk, 0, stream>>>(
                hb, 4096, w2b + (size_t)n * 1024 * 4096, 4096, b2 + (size_t)n * 1024,
                eob, 1024, 4096, eid, -1);
            // kv rows (m*8+n): C base kvb + (m0*8+n)*2048, ldc = 16384
            gemm_nt<false, ushort><<<dim3(16, Mc / 128), blk, 0, stream>>>(
                eob, 1024, ipwb + (size_t)1024 * 1024, 1024, ipb + 1024,
                kvb + (m0 * 8 + n) * 2048, 16384, 1024, eid, -1);
            // q = eo @ wq^T + bq, only for n == expert_id
            gemm_nt<false, ushort><<<dim3(8, Mc / 128), blk, 0, stream>>>(
                eob, 1024, ipwb, 1024, ipb,
                qb + m0 * 1024, 1024, 1024, eid, n);
        }
    }

    // ---- attention: one block per (b,s) ----
    attn_kernel<<<dim3(8192), blk, 0, stream>>>(qb, kvb, eid, o3b);

    // ---- out = o3 @ out_w^T + out_b -> fp32 d_out ----
    gemm_nt<false, float><<<dim3(8, 64), blk, 0, stream>>>(
        o3b, 1024, owb, 1024, ob,
        (float*)d_out, 1024, 1024, eid, -1);
}

// Round 3
// 2665.790 us; speedup vs baseline: 2.0302x; 2.0302x over previous
//
#include <hip/hip_runtime.h>

// ---------- types / helpers ----------
typedef __bf16 bf16x8 __attribute__((ext_vector_type(8)));
typedef float  f32x4  __attribute__((ext_vector_type(4)));

__device__ __forceinline__ float bf2f(unsigned short u) {
    union { unsigned int i; float f; } x; x.i = ((unsigned int)u) << 16; return x.f;
}
__device__ __forceinline__ unsigned short f2bf(float f) {
    union { float f; unsigned int i; } x; x.f = f;
    unsigned int r = x.i + 0x7fff + ((x.i >> 16) & 1);   // RNE
    return (unsigned short)(r >> 16);
}

__device__ __forceinline__ void gload16(const void* g, void* l) {
    __builtin_amdgcn_global_load_lds(
        (const __attribute__((address_space(1))) void*)g,
        (__attribute__((address_space(3))) void*)l, 16, 0, 0);
}

// ---------- fp32 -> bf16 conversion (vectorized, grid-stride) ----------
__global__ __launch_bounds__(256) void cvt_f32_bf16(
    const float4* __restrict__ in, ushort4* __restrict__ out, long n4)
{
    long i = (long)blockIdx.x * blockDim.x + threadIdx.x;
    const long stride = (long)gridDim.x * blockDim.x;
    for (; i < n4; i += stride) {
        const float4 v = in[i];
        ushort4 o = { f2bf(v.x), f2bf(v.y), f2bf(v.z), f2bf(v.w) };
        out[i] = o;
    }
}

// ---------- z-batched NT GEMM ----------
// C[z][m,n] = sum_k A[z][m,k]*B[z][n,k] (+bias[z][n] fp32, opt relu)
// z = blockIdx.z, or *eid_p when eidSel (device-side expert select).
// A,B bf16 row-major K-contiguous; C bf16 (CT=ushort) or fp32 (CT=float).
// 128x128 tile, BK=32, 256 threads (4 waves, 2x2 of 64x64).
template<bool RELU, typename CT>
__global__ __launch_bounds__(256, 4) void gemm_nt(
    const ushort* __restrict__ A, long lda, long sAz,
    const ushort* __restrict__ B, long ldb, long sBz,
    const float* __restrict__ bias, long sBiasz,
    CT* __restrict__ C, long ldc, long sCz,
    int K, const int* __restrict__ eid_p, int eidSel)
{
    const long z = eidSel ? (long)(*eid_p) : (long)blockIdx.z;
    A    += z * sAz;
    B    += z * sBz;
    bias += z * sBiasz;
    C    += z * sCz;

    __shared__ alignas(16) ushort As[128 * 32];
    __shared__ alignas(16) ushort Bs[128 * 32];

    const int t    = threadIdx.x;
    const int w    = t >> 6;
    const int lane = t & 63;
    const int lr   = lane & 15;
    const int lq   = lane >> 4;
    const int wm   = (w >> 1) * 64;
    const int wn   = (w & 1) * 64;
    const long m0  = (long)blockIdx.y * 128;
    const long n0  = (long)blockIdx.x * 128;

    // staging: thread t loads 16B: row = t>>2 (0..63), k-chunk = (t&3)*8
    const int srow   = t >> 2;
    const int schunk = (t & 3) * 8;
    const ushort* aG = A + (m0 + srow) * lda + schunk;
    const ushort* bG = B + (n0 + srow) * ldb + schunk;
    char* lA = (char*)As + w * 1024;   // wave-uniform LDS base; HW appends lane*16
    char* lB = (char*)Bs + w * 1024;

    f32x4 acc[4][4];
#pragma unroll
    for (int i = 0; i < 4; i++)
#pragma unroll
        for (int j = 0; j < 4; j++) acc[i][j] = (f32x4){0.f, 0.f, 0.f, 0.f};

    for (int kt = 0; kt < K; kt += 32) {
        gload16(aG,            lA);
        gload16(aG + 64 * lda, lA + 4096);
        gload16(bG,            lB);
        gload16(bG + 64 * ldb, lB + 4096);
        aG += 32; bG += 32;
        __syncthreads();

        bf16x8 af[4], bf[4];
#pragma unroll
        for (int i = 0; i < 4; i++)
            af[i] = *(const bf16x8*)&As[(wm + i * 16 + lr) * 32 + lq * 8];
#pragma unroll
        for (int j = 0; j < 4; j++)
            bf[j] = *(const bf16x8*)&Bs[(wn + j * 16 + lr) * 32 + lq * 8];
#pragma unroll
        for (int i = 0; i < 4; i++)
#pragma unroll
            for (int j = 0; j < 4; j++)
                acc[i][j] = __builtin_amdgcn_mfma_f32_16x16x32_bf16(af[i], bf[j], acc[i][j], 0, 0, 0);
        __syncthreads();
    }

    // epilogue: row = m0+wm+i*16+lq*4+r, col = n0+wn+j*16+lr
#pragma unroll
    for (int j = 0; j < 4; j++) {
        const long col = n0 + wn + j * 16 + lr;
        const float bv = bias[col];
#pragma unroll
        for (int i = 0; i < 4; i++) {
            const long rbase = m0 + wm + i * 16 + lq * 4;
#pragma unroll
            for (int r = 0; r < 4; r++) {
                float v = acc[i][j][r] + bv;
                if (RELU) v = fmaxf(v, 0.f);
                if constexpr (__is_same(CT, ushort)) C[(rbase + r) * ldc + col] = f2bf(v);
                else                                 C[(rbase + r) * ldc + col] = v;
            }
        }
    }
}

// ---------- attention over the expert axis ----------
// per (b,s)=m, head h (16): logits[n] = q.k[n]/8 + (n<=eid), softmax, o = sum attn*v.
// kv layout: row (m*8+n), 2048 wide: k @ [0,1024), v @ [1024,2048).
__global__ __launch_bounds__(256) void attn_kernel(
    const ushort* __restrict__ q, const ushort* __restrict__ kv,
    const int* __restrict__ eid_p, ushort* __restrict__ o3)
{
    const size_t m = blockIdx.x;
    const int t    = threadIdx.x;
    const int h    = t >> 4;
    const int d0   = (t & 15) * 4;
    const int eid  = *eid_p;

    const ushort4 qu = *(const ushort4*)(q + m * 1024 + h * 64 + d0);
    const float qv[4] = { bf2f(qu.x), bf2f(qu.y), bf2f(qu.z), bf2f(qu.w) };

    float l[8];
#pragma unroll
    for (int n = 0; n < 8; n++) {
        const ushort4 ku = *(const ushort4*)(kv + (m * 8 + n) * 2048 + h * 64 + d0);
        float p = qv[0] * bf2f(ku.x) + qv[1] * bf2f(ku.y) + qv[2] * bf2f(ku.z) + qv[3] * bf2f(ku.w);
        p += __shfl_xor(p, 1);
        p += __shfl_xor(p, 2);
        p += __shfl_xor(p, 4);
        p += __shfl_xor(p, 8);
        l[n] = p * 0.125f + ((n <= eid) ? 1.0f : 0.0f);
    }
    float mx = l[0];
#pragma unroll
    for (int n = 1; n < 8; n++) mx = fmaxf(mx, l[n]);
    float e[8], s = 0.f;
#pragma unroll
    for (int n = 0; n < 8; n++) { e[n] = __expf(l[n] - mx); s += e[n]; }
    const float inv = 1.f / s;

    float o[4] = {0.f, 0.f, 0.f, 0.f};
#pragma unroll
    for (int n = 0; n < 8; n++) {
        const ushort4 vu = *(const ushort4*)(kv + (m * 8 + n) * 2048 + 1024 + h * 64 + d0);
        const float a = e[n] * inv;
        o[0] += a * bf2f(vu.x); o[1] += a * bf2f(vu.y);
        o[2] += a * bf2f(vu.z); o[3] += a * bf2f(vu.w);
    }
    ushort4 ou = { f2bf(o[0]), f2bf(o[1]), f2bf(o[2]), f2bf(o[3]) };
    *(ushort4*)(o3 + m * 1024 + h * 64 + d0) = ou;
}

// ---------- launch ----------
extern "C" void kernel_launch(void* const* d_in, const int* in_sizes, int n_in,
                              void* d_out, int out_size, void* d_ws, size_t ws_size,
                              hipStream_t stream)
{
    const float* x   = (const float*)d_in[0];
    const float* w1  = (const float*)d_in[1];
    const float* b1  = (const float*)d_in[2];
    const float* w2  = (const float*)d_in[3];
    const float* b2  = (const float*)d_in[4];
    const float* ipw = (const float*)d_in[5];
    const float* ipb = (const float*)d_in[6];
    const float* ow  = (const float*)d_in[7];
    const float* ob  = (const float*)d_in[8];
    const int*   eid = (const int*)d_in[9];

    // ---- workspace layout ----
    char* ws = (char*)d_ws;
    size_t off = 0;
    auto alloc = [&](size_t bytes) { char* p = ws + off; off += (bytes + 255) & ~(size_t)255; return p; };
    ushort* w1b  = (ushort*)alloc(8LL * 4096 * 1024 * 2);   //  67.1 MB
    ushort* w2b  = (ushort*)alloc(8LL * 1024 * 4096 * 2);   //  67.1 MB
    ushort* ipwb = (ushort*)alloc(3LL * 1024 * 1024 * 2);   //   6.3 MB
    ushort* owb  = (ushort*)alloc(1LL * 1024 * 1024 * 2);   //   2.1 MB
    ushort* xb   = (ushort*)alloc(8192LL * 1024 * 2);       //  16.8 MB
    ushort* kvb  = (ushort*)alloc(8192LL * 8 * 2048 * 2);   // 268.4 MB
    ushort* qb   = (ushort*)alloc(8192LL * 1024 * 2);       //  16.8 MB
    const size_t fixed = off;

    // chunked transients: hb [8][Mc][4096] + eob [8][Mc][1024] bf16
    long Mc = 8192;
    while (Mc > 256 && fixed + (size_t)Mc * 81920 + 1024 > ws_size) Mc >>= 1;
    ushort* hb  = (ushort*)alloc((size_t)Mc * 8 * 4096 * 2);
    ushort* eob = (ushort*)alloc((size_t)Mc * 8 * 1024 * 2);
    // o3b aliases hb (hb is dead once the chunk loop finishes); Mc>=256 => hb >= 16.8MB
    ushort* o3b = hb;

    const dim3 blk(256);
    const dim3 cgrid(2048);

    // ---- fp32 -> bf16 conversions (weights + x); biases stay fp32 ----
    cvt_f32_bf16<<<cgrid, blk, 0, stream>>>((const float4*)w1,  (ushort4*)w1b,  8LL * 4096 * 1024 / 4);
    cvt_f32_bf16<<<cgrid, blk, 0, stream>>>((const float4*)w2,  (ushort4*)w2b,  8LL * 1024 * 4096 / 4);
    cvt_f32_bf16<<<cgrid, blk, 0, stream>>>((const float4*)ipw, (ushort4*)ipwb, 3LL * 1024 * 1024 / 4);
    cvt_f32_bf16<<<cgrid, blk, 0, stream>>>((const float4*)ow,  (ushort4*)owb,  1LL * 1024 * 1024 / 4);
    cvt_f32_bf16<<<cgrid, blk, 0, stream>>>((const float4*)x,   (ushort4*)xb,   8192LL * 1024 / 4);

    // ---- chunked over M, z-batched over experts ----
    for (long m0 = 0; m0 < 8192; m0 += Mc) {
        const unsigned my = (unsigned)(Mc / 128);
        // h[z] = relu(x @ w1[z]^T + b1[z]) : Mc x 4096, K=1024
        gemm_nt<true, ushort><<<dim3(32, my, 8), blk, 0, stream>>>(
            xb + m0 * 1024, 1024, 0,
            w1b, 1024, 4096LL * 1024,
            b1, 4096,
            hb, 4096, (long)Mc * 4096,
            1024, eid, 0);
        // eo[z] = h[z] @ w2[z]^T + b2[z] : Mc x 1024, K=4096
        gemm_nt<false, ushort><<<dim3(8, my, 8), blk, 0, stream>>>(
            hb, 4096, (long)Mc * 4096,
            w2b, 4096, 1024LL * 4096,
            b2, 1024,
            eob, 1024, (long)Mc * 1024,
            4096, eid, 0);
        // kv[z] = eo[z] @ [wk;wv]^T + [bk;bv] : Mc x 2048, K=1024
        // C row m -> kvb[(m0+m)*8*2048 + z*2048 + col], ldc=16384
        gemm_nt<false, ushort><<<dim3(16, my, 8), blk, 0, stream>>>(
            eob, 1024, (long)Mc * 1024,
            ipwb + (size_t)1024 * 1024, 1024, 0,
            ipb + 1024, 0,
            kvb + m0 * 16384, 16384, 2048,
            1024, eid, 0);
        // q = eo[*eid] @ wq^T + bq : Mc x 1024, K=1024 (device-side expert select)
        gemm_nt<false, ushort><<<dim3(8, my, 1), blk, 0, stream>>>(
            eob, 1024, (long)Mc * 1024,
            ipwb, 1024, 0,
            ipb, 0,
            qb + m0 * 1024, 1024, 0,
            1024, eid, 1);
    }

    // ---- attention: one block per (b,s) ----
    attn_kernel<<<dim3(8192), blk, 0, stream>>>(qb, kvb, eid, o3b);

    // ---- out = o3 @ out_w^T + out_b -> fp32 d_out ----
    gemm_nt<false, float><<<dim3(8, 64, 1), blk, 0, stream>>>(
        o3b, 1024, 0,
        owb, 1024, 0,
        ob, 0,
        (float*)d_out, 1024, 0,
        1024, eid, 0);
}

// Round 4
// 2461.143 us; speedup vs baseline: 2.1990x; 1.0832x over previous
//
#include <hip/hip_runtime.h>

// ---------- types / helpers ----------
typedef __bf16 bf16x8 __attribute__((ext_vector_type(8)));
typedef float  f32x4  __attribute__((ext_vector_type(4)));

__device__ __forceinline__ float bf2f(unsigned short u) {
    union { unsigned int i; float f; } x; x.i = ((unsigned int)u) << 16; return x.f;
}
__device__ __forceinline__ unsigned short f2bf(float f) {
    union { float f; unsigned int i; } x; x.f = f;
    unsigned int r = x.i + 0x7fff + ((x.i >> 16) & 1);   // RNE
    return (unsigned short)(r >> 16);
}

__device__ __forceinline__ void gload16(const void* g, void* l) {
    __builtin_amdgcn_global_load_lds(
        (const __attribute__((address_space(1))) void*)g,
        (__attribute__((address_space(3))) void*)l, 16, 0, 0);
}

// ---------- fp32 -> bf16 conversion (vectorized, grid-stride) ----------
__global__ __launch_bounds__(256) void cvt_f32_bf16(
    const float4* __restrict__ in, ushort4* __restrict__ out, long n4)
{
    long i = (long)blockIdx.x * blockDim.x + threadIdx.x;
    const long stride = (long)gridDim.x * blockDim.x;
    for (; i < n4; i += stride) {
        const float4 v = in[i];
        ushort4 o = { f2bf(v.x), f2bf(v.y), f2bf(v.z), f2bf(v.w) };
        out[i] = o;
    }
}

// ---------- shared GEMM core macro-ish helpers ----------
// 128x128 tile, BK=32, 256 threads (4 waves, 2x2 of 64x64 sub-tiles).
// acc layout: C row = m0+wm+i*16+lq*4+r, col = n0+wn+j*16+lr.

// ---------- z-batched NT GEMM: C[z][m,n] = sum_k A[z][m,k]*B[z][n,k] (+bias, opt relu) ----------
template<bool RELU, typename CT>
__global__ __launch_bounds__(256, 4) void gemm_nt(
    const ushort* __restrict__ A, long lda, long sAz,
    const ushort* __restrict__ B, long ldb, long sBz,
    const float* __restrict__ bias, long sBiasz,
    CT* __restrict__ C, long ldc, long sCz,
    int K)
{
    const long z = blockIdx.z;
    A    += z * sAz;
    B    += z * sBz;
    bias += z * sBiasz;
    C    += z * sCz;

    __shared__ alignas(16) ushort As[128 * 32];
    __shared__ alignas(16) ushort Bs[128 * 32];

    const int t    = threadIdx.x;
    const int w    = t >> 6;
    const int lane = t & 63;
    const int lr   = lane & 15;
    const int lq   = lane >> 4;
    const int wm   = (w >> 1) * 64;
    const int wn   = (w & 1) * 64;
    const long m0  = (long)blockIdx.y * 128;
    const long n0  = (long)blockIdx.x * 128;

    const int srow   = t >> 2;
    const int schunk = (t & 3) * 8;
    const ushort* aG = A + (m0 + srow) * lda + schunk;
    const ushort* bG = B + (n0 + srow) * ldb + schunk;
    char* lA = (char*)As + w * 1024;   // wave-uniform LDS base; HW appends lane*16
    char* lB = (char*)Bs + w * 1024;

    f32x4 acc[4][4];
#pragma unroll
    for (int i = 0; i < 4; i++)
#pragma unroll
        for (int j = 0; j < 4; j++) acc[i][j] = (f32x4){0.f, 0.f, 0.f, 0.f};

    for (int kt = 0; kt < K; kt += 32) {
        gload16(aG,            lA);
        gload16(aG + 64 * lda, lA + 4096);
        gload16(bG,            lB);
        gload16(bG + 64 * ldb, lB + 4096);
        aG += 32; bG += 32;
        __syncthreads();

        bf16x8 af[4], bf[4];
#pragma unroll
        for (int i = 0; i < 4; i++)
            af[i] = *(const bf16x8*)&As[(wm + i * 16 + lr) * 32 + lq * 8];
#pragma unroll
        for (int j = 0; j < 4; j++)
            bf[j] = *(const bf16x8*)&Bs[(wn + j * 16 + lr) * 32 + lq * 8];
#pragma unroll
        for (int i = 0; i < 4; i++)
#pragma unroll
            for (int j = 0; j < 4; j++)
                acc[i][j] = __builtin_amdgcn_mfma_f32_16x16x32_bf16(af[i], bf[j], acc[i][j], 0, 0, 0);
        __syncthreads();
    }

#pragma unroll
    for (int j = 0; j < 4; j++) {
        const long col = n0 + wn + j * 16 + lr;
        const float bv = bias[col];
#pragma unroll
        for (int i = 0; i < 4; i++) {
            const long rbase = m0 + wm + i * 16 + lq * 4;
#pragma unroll
            for (int r = 0; r < 4; r++) {
                float v = acc[i][j][r] + bv;
                if (RELU) v = fmaxf(v, 0.f);
                if constexpr (__is_same(CT, ushort)) C[(rbase + r) * ldc + col] = f2bf(v);
                else                                 C[(rbase + r) * ldc + col] = v;
            }
        }
    }
}

// ---------- fused QKV projection (z-batched over experts) ----------
// A = eob [z][Mc][1024]; B = ipwb (3072 x 1024): rows 0..1023 wq, 1024..3071 wk|wv.
// n-tiles 0..7  -> q (only when z == *eid): qc[m*1024 + col]
// n-tiles 8..23 -> kv interleaved: kvc[m*16384 + z*2048 + (col-1024)]
__global__ __launch_bounds__(256, 4) void gemm_qkv(
    const ushort* __restrict__ A, long lda, long sAz,
    const ushort* __restrict__ B, long ldb,
    const float* __restrict__ bias,
    ushort* __restrict__ qc,
    ushort* __restrict__ kvc,
    int K, const int* __restrict__ eid_p)
{
    const long z   = blockIdx.z;
    const long n0  = (long)blockIdx.x * 128;   // 0..2944 global col
    const bool isq = (n0 < 1024);
    if (isq && z != (long)(*eid_p)) return;
    A += z * sAz;

    __shared__ alignas(16) ushort As[128 * 32];
    __shared__ alignas(16) ushort Bs[128 * 32];

    const int t    = threadIdx.x;
    const int w    = t >> 6;
    const int lane = t & 63;
    const int lr   = lane & 15;
    const int lq   = lane >> 4;
    const int wm   = (w >> 1) * 64;
    const int wn   = (w & 1) * 64;
    const long m0  = (long)blockIdx.y * 128;

    const int srow   = t >> 2;
    const int schunk = (t & 3) * 8;
    const ushort* aG = A + (m0 + srow) * lda + schunk;
    const ushort* bG = B + (n0 + srow) * ldb + schunk;
    char* lA = (char*)As + w * 1024;
    char* lB = (char*)Bs + w * 1024;

    f32x4 acc[4][4];
#pragma unroll
    for (int i = 0; i < 4; i++)
#pragma unroll
        for (int j = 0; j < 4; j++) acc[i][j] = (f32x4){0.f, 0.f, 0.f, 0.f};

    for (int kt = 0; kt < K; kt += 32) {
        gload16(aG,            lA);
        gload16(aG + 64 * lda, lA + 4096);
        gload16(bG,            lB);
        gload16(bG + 64 * ldb, lB + 4096);
        aG += 32; bG += 32;
        __syncthreads();

        bf16x8 af[4], bf[4];
#pragma unroll
        for (int i = 0; i < 4; i++)
            af[i] = *(const bf16x8*)&As[(wm + i * 16 + lr) * 32 + lq * 8];
#pragma unroll
        for (int j = 0; j < 4; j++)
            bf[j] = *(const bf16x8*)&Bs[(wn + j * 16 + lr) * 32 + lq * 8];
#pragma unroll
        for (int i = 0; i < 4; i++)
#pragma unroll
            for (int j = 0; j < 4; j++)
                acc[i][j] = __builtin_amdgcn_mfma_f32_16x16x32_bf16(af[i], bf[j], acc[i][j], 0, 0, 0);
        __syncthreads();
    }

#pragma unroll
    for (int j = 0; j < 4; j++) {
        const long col = n0 + wn + j * 16 + lr;      // global col in [0,3072)
        const float bv = bias[col];
#pragma unroll
        for (int i = 0; i < 4; i++) {
            const long rbase = m0 + wm + i * 16 + lq * 4;
#pragma unroll
            for (int r = 0; r < 4; r++) {
                const float v = acc[i][j][r] + bv;
                const long row = rbase + r;
                if (isq) qc[row * 1024 + col] = f2bf(v);
                else     kvc[row * 16384 + z * 2048 + (col - 1024)] = f2bf(v);
            }
        }
    }
}

// ---------- attention over the expert axis (chunk-local) ----------
// per local row m, head h (16): logits[n] = q.k[n]/8 + (n<=eid), softmax, o = sum a*v.
// kvc row (m*8+n), 2048 wide: k @ [0,1024), v @ [1024,2048).
__global__ __launch_bounds__(256) void attn_kernel(
    const ushort* __restrict__ qc, const ushort* __restrict__ kvc,
    const int* __restrict__ eid_p, ushort* __restrict__ o3)
{
    const size_t m = blockIdx.x;
    const int t    = threadIdx.x;
    const int h    = t >> 4;
    const int d0   = (t & 15) * 4;
    const int eid  = *eid_p;

    const ushort4 qu = *(const ushort4*)(qc + m * 1024 + h * 64 + d0);
    const float qv[4] = { bf2f(qu.x), bf2f(qu.y), bf2f(qu.z), bf2f(qu.w) };

    float l[8];
#pragma unroll
    for (int n = 0; n < 8; n++) {
        const ushort4 ku = *(const ushort4*)(kvc + (m * 8 + n) * 2048 + h * 64 + d0);
        float p = qv[0] * bf2f(ku.x) + qv[1] * bf2f(ku.y) + qv[2] * bf2f(ku.z) + qv[3] * bf2f(ku.w);
        p += __shfl_xor(p, 1);
        p += __shfl_xor(p, 2);
        p += __shfl_xor(p, 4);
        p += __shfl_xor(p, 8);
        l[n] = p * 0.125f + ((n <= eid) ? 1.0f : 0.0f);
    }
    float mx = l[0];
#pragma unroll
    for (int n = 1; n < 8; n++) mx = fmaxf(mx, l[n]);
    float e[8], s = 0.f;
#pragma unroll
    for (int n = 0; n < 8; n++) { e[n] = __expf(l[n] - mx); s += e[n]; }
    const float inv = 1.f / s;

    float o[4] = {0.f, 0.f, 0.f, 0.f};
#pragma unroll
    for (int n = 0; n < 8; n++) {
        const ushort4 vu = *(const ushort4*)(kvc + (m * 8 + n) * 2048 + 1024 + h * 64 + d0);
        const float a = e[n] * inv;
        o[0] += a * bf2f(vu.x); o[1] += a * bf2f(vu.y);
        o[2] += a * bf2f(vu.z); o[3] += a * bf2f(vu.w);
    }
    ushort4 ou = { f2bf(o[0]), f2bf(o[1]), f2bf(o[2]), f2bf(o[3]) };
    *(ushort4*)(o3 + m * 1024 + h * 64 + d0) = ou;
}

// ---------- launch ----------
extern "C" void kernel_launch(void* const* d_in, const int* in_sizes, int n_in,
                              void* d_out, int out_size, void* d_ws, size_t ws_size,
                              hipStream_t stream)
{
    const float* x   = (const float*)d_in[0];
    const float* w1  = (const float*)d_in[1];
    const float* b1  = (const float*)d_in[2];
    const float* w2  = (const float*)d_in[3];
    const float* b2  = (const float*)d_in[4];
    const float* ipw = (const float*)d_in[5];
    const float* ipb = (const float*)d_in[6];
    const float* ow  = (const float*)d_in[7];
    const float* ob  = (const float*)d_in[8];
    const int*   eid = (const int*)d_in[9];

    // ---- workspace layout ----
    char* ws = (char*)d_ws;
    size_t off = 0;
    auto alloc = [&](size_t bytes) { char* p = ws + off; off += (bytes + 255) & ~(size_t)255; return p; };
    ushort* w1b  = (ushort*)alloc(8LL * 4096 * 1024 * 2);   //  67.1 MB
    ushort* w2b  = (ushort*)alloc(8LL * 1024 * 4096 * 2);   //  67.1 MB
    ushort* ipwb = (ushort*)alloc(3LL * 1024 * 1024 * 2);   //   6.3 MB
    ushort* owb  = (ushort*)alloc(1LL * 1024 * 1024 * 2);   //   2.1 MB
    ushort* xb   = (ushort*)alloc(8192LL * 1024 * 2);       //  16.8 MB
    ushort* o3b  = (ushort*)alloc(8192LL * 1024 * 2);       //  16.8 MB
    const size_t fixed = off;

    // per-chunk transients: hb [8][Mc][4096] + eob [8][Mc][1024] + kvc [Mc][8][2048] + qc [Mc][1024]
    // bytes per Mc row: 65536 + 16384 + 32768 + 2048 = 116736
    long Mc = 2048;
    while (Mc > 256 && fixed + (size_t)Mc * 116736 + 2048 > ws_size) Mc >>= 1;
    ushort* hb  = (ushort*)alloc((size_t)Mc * 8 * 4096 * 2);
    ushort* eob = (ushort*)alloc((size_t)Mc * 8 * 1024 * 2);
    ushort* kvc = (ushort*)alloc((size_t)Mc * 8 * 2048 * 2);
    ushort* qc  = (ushort*)alloc((size_t)Mc * 1024 * 2);

    const dim3 blk(256);
    const dim3 cgrid(2048);

    // ---- fp32 -> bf16 conversions (weights + x); biases stay fp32 ----
    cvt_f32_bf16<<<cgrid, blk, 0, stream>>>((const float4*)w1,  (ushort4*)w1b,  8LL * 4096 * 1024 / 4);
    cvt_f32_bf16<<<cgrid, blk, 0, stream>>>((const float4*)w2,  (ushort4*)w2b,  8LL * 1024 * 4096 / 4);
    cvt_f32_bf16<<<cgrid, blk, 0, stream>>>((const float4*)ipw, (ushort4*)ipwb, 3LL * 1024 * 1024 / 4);
    cvt_f32_bf16<<<cgrid, blk, 0, stream>>>((const float4*)ow,  (ushort4*)owb,  1LL * 1024 * 1024 / 4);
    cvt_f32_bf16<<<cgrid, blk, 0, stream>>>((const float4*)x,   (ushort4*)xb,   8192LL * 1024 / 4);

    // ---- chunked over M; everything inside is z-batched over the 8 experts ----
    for (long m0 = 0; m0 < 8192; m0 += Mc) {
        const unsigned my = (unsigned)(Mc / 128);
        // h[z] = relu(x @ w1[z]^T + b1[z]) : Mc x 4096, K=1024
        gemm_nt<true, ushort><<<dim3(32, my, 8), blk, 0, stream>>>(
            xb + m0 * 1024, 1024, 0,
            w1b, 1024, 4096LL * 1024,
            b1, 4096,
            hb, 4096, (long)Mc * 4096,
            1024);
        // eo[z] = h[z] @ w2[z]^T + b2[z] : Mc x 1024, K=4096
        gemm_nt<false, ushort><<<dim3(8, my, 8), blk, 0, stream>>>(
            hb, 4096, (long)Mc * 4096,
            w2b, 4096, 1024LL * 4096,
            b2, 1024,
            eob, 1024, (long)Mc * 1024,
            4096);
        // q/k/v projections fused: N = 3072 (q tiles active only for z == eid)
        gemm_qkv<<<dim3(24, my, 8), blk, 0, stream>>>(
            eob, 1024, (long)Mc * 1024,
            ipwb, 1024,
            ipb,
            qc, kvc,
            1024, eid);
        // attention for this chunk's rows -> o3b[m0..m0+Mc)
        attn_kernel<<<dim3((unsigned)Mc), blk, 0, stream>>>(
            qc, kvc, eid, o3b + m0 * 1024);
    }

    // ---- out = o3 @ out_w^T + out_b -> fp32 d_out : 8192 x 1024, K=1024 ----
    gemm_nt<false, float><<<dim3(8, 64, 1), blk, 0, stream>>>(
        o3b, 1024, 0,
        owb, 1024, 0,
        ob, 0,
        (float*)d_out, 1024, 0,
        1024);
}